// Round 5
// baseline (318.477 us; speedup 1.0000x reference)
//
#include <hip/hip_runtime.h>
#include <hip/hip_bf16.h>
#include <math.h>

#define E_ 768
#define HID_ 1536
#define SQ_ 1024

typedef unsigned short u16;
using bf16x8 = __attribute__((ext_vector_type(8))) __bf16;
using f32x4  = __attribute__((ext_vector_type(4))) float;

__device__ __forceinline__ u16 f2bf(float f) {
  union { float f; unsigned u; } v; v.f = f;
  unsigned r = v.u + 0x7FFFu + ((v.u >> 16) & 1u);
  return (u16)(r >> 16);
}
__device__ __forceinline__ float bf2f(u16 h) {
  union { unsigned u; float f; } v; v.u = ((unsigned)h) << 16; return v.f;
}
__device__ __forceinline__ float gelu_f(float x) {
  return 0.5f * x * (1.0f + erff(x * 0.70710678118654752f));
}

#define GLDS16(gp, sp) __builtin_amdgcn_global_load_lds( \
    (__attribute__((address_space(1))) const void*)(const void*)(gp), \
    (__attribute__((address_space(3))) void*)(void*)(sp), 16, 0, 0)

// ---------------- prep: cast x -> bf16; LDS-tiled transpose-cast W1->W1T, W2->W2T
__global__ void prep_kernel(const float* __restrict__ x, const float* __restrict__ W1,
                            const float* __restrict__ W2, u16* __restrict__ xb,
                            u16* __restrict__ W1T, u16* __restrict__ W2T) {
  __shared__ float T[64 * 65];
  int bid = blockIdx.x, t = threadIdx.x;
  if (bid < 6144) {                       // x: 6144*1024 = 6291456 elems
    int base = bid * 1024 + t * 4;
    const float4 v = *reinterpret_cast<const float4*>(x + base);
    ushort4 o; o.x = f2bf(v.x); o.y = f2bf(v.y); o.z = f2bf(v.z); o.w = f2bf(v.w);
    *reinterpret_cast<ushort4*>(xb + base) = o;
    return;
  }
  const float* in; u16* out; int R_in, C_in, rt, ct;
  if (bid < 6432) {                       // W1 (768 x 1536) -> W1T (1536 x 768)
    int b2 = bid - 6144; in = W1; out = W1T; R_in = 768; C_in = 1536;
    rt = b2 / 24; ct = b2 % 24;
  } else {                                // W2 (1536 x 768) -> W2T (768 x 1536)
    int b3 = bid - 6432; in = W2; out = W2T; R_in = 1536; C_in = 768;
    rt = b3 / 12; ct = b3 % 12;
  }
  int r0 = rt << 6, c0 = ct << 6;
  int tr = t >> 4, tc4 = (t & 15) << 2;
#pragma unroll
  for (int i = 0; i < 4; ++i) {
    int row = tr + (i << 4);
    const float4 v = *reinterpret_cast<const float4*>(in + (size_t)(r0 + row) * C_in + c0 + tc4);
    T[row * 65 + tc4 + 0] = v.x;
    T[row * 65 + tc4 + 1] = v.y;
    T[row * 65 + tc4 + 2] = v.z;
    T[row * 65 + tc4 + 3] = v.w;
  }
  __syncthreads();
#pragma unroll
  for (int i = 0; i < 4; ++i) {
    int orow = tr + (i << 4);
    ushort4 o;
    o.x = f2bf(T[(tc4 + 0) * 65 + orow]);
    o.y = f2bf(T[(tc4 + 1) * 65 + orow]);
    o.z = f2bf(T[(tc4 + 2) * 65 + orow]);
    o.w = f2bf(T[(tc4 + 3) * 65 + orow]);
    *reinterpret_cast<ushort4*>(out + (size_t)(c0 + orow) * R_in + r0 + tc4) = o;
  }
}

// ---------------- rowsum partials over 4 s-chunks (reads bf16 xb) ---------------
__global__ void rowsum_kernel(const u16* __restrict__ xb, float* __restrict__ Rp) {
  int bid = blockIdx.x;          // 384 = r(96)*4 + c
  int r = bid >> 2, c = bid & 3;
  int b = r / 12, n = r % 12;
  int t = threadIdx.x;
  int u0 = n << 10;
  int s_lo = u0 / 12;
  int s_hi = (u0 + 1023) / 12;
  int cnt = s_hi - s_lo + 1;
  int cs = s_lo + (cnt * c) / 4;
  int ce = s_lo + (cnt * (c + 1)) / 4;
  float acc[12][3];
#pragma unroll
  for (int g = 0; g < 12; ++g)
    for (int q = 0; q < 3; ++q) acc[g][q] = 0.f;
  const u16* xp = xb + (size_t)b * SQ_ * E_;
  for (int s = cs; s < ce; ++s) {
    float v0 = bf2f(xp[(size_t)s * E_ + t]);
    float v1 = bf2f(xp[(size_t)s * E_ + t + 256]);
    float v2 = bf2f(xp[(size_t)s * E_ + t + 512]);
    int du = 12 * s - u0;
#pragma unroll
    for (int g = 0; g < 12; ++g) {
      int u = du + g;
      if (u >= 0 && u < 1024) { acc[g][0] += v0; acc[g][1] += v1; acc[g][2] += v2; }
    }
  }
  float* Rr = Rp + (size_t)bid * 9216;
#pragma unroll
  for (int g = 0; g < 12; ++g) {
    Rr[g * 768 + t]       = acc[g][0];
    Rr[g * 768 + t + 256] = acc[g][1];
    Rr[g * 768 + t + 512] = acc[g][2];
  }
}

// ---- P3[r][g][jc][d] = sum_{j in jc-chunk} (sum_c Rp[r,c,g,j]) * Wv[j, g*64+d] -
__global__ void ygemm_kernel(const float* __restrict__ Rp, const float* __restrict__ Wv,
                             float* __restrict__ P3) {
  int g = blockIdx.x, r = blockIdx.y, jc = blockIdx.z;   // (12, 96, 8)
  int t = threadIdx.x;
  int d = t & 63, sub = t >> 6;
  const float* R0 = Rp + (size_t)r * 4 * 9216 + g * 768;
  const float* wp = Wv + g * 64 + d;
  int j0 = jc * 96 + sub * 24;
  float a0 = 0.f, a1 = 0.f, a2 = 0.f, a3 = 0.f;
#pragma unroll
  for (int jj = 0; jj < 24; jj += 4) {
    int j = j0 + jj;
    float r0v = R0[j + 0] + R0[9216 + j + 0] + R0[18432 + j + 0] + R0[27648 + j + 0];
    float r1v = R0[j + 1] + R0[9216 + j + 1] + R0[18432 + j + 1] + R0[27648 + j + 1];
    float r2v = R0[j + 2] + R0[9216 + j + 2] + R0[18432 + j + 2] + R0[27648 + j + 2];
    float r3v = R0[j + 3] + R0[9216 + j + 3] + R0[18432 + j + 3] + R0[27648 + j + 3];
    a0 += r0v * wp[(size_t)(j + 0) * 768];
    a1 += r1v * wp[(size_t)(j + 1) * 768];
    a2 += r2v * wp[(size_t)(j + 2) * 768];
    a3 += r3v * wp[(size_t)(j + 3) * 768];
  }
  __shared__ float red[256];
  red[t] = (a0 + a1) + (a2 + a3);
  __syncthreads();
  if (sub == 0)
    P3[(((size_t)r * 12 + g) * 8 + jc) * 64 + d] = red[d] + red[64 + d] + red[128 + d] + red[192 + d];
}

// ---------------- LN1 over Y[b,:] (768) -> L1[b,:] ------------------------------
__global__ void ln1_kernel(const float* __restrict__ P3, const float* __restrict__ g1,
                           const float* __restrict__ be1, float* __restrict__ L1) {
  int b = blockIdx.x, t = threadIdx.x;
  float y[3];
#pragma unroll
  for (int q = 0; q < 3; ++q) {
    int e = t + (q << 8);
    int n = e >> 6, d = e & 63;
    const float* Pp = P3 + (size_t)(b * 12 + n) * 96 * 64 + d;
    float s = 0.f;
#pragma unroll 8
    for (int gj = 0; gj < 96; ++gj) s += Pp[gj << 6];
    y[q] = s;
  }
  float s = y[0] + y[1] + y[2];
  float sq = y[0] * y[0] + y[1] * y[1] + y[2] * y[2];
  __shared__ float red[8];
#pragma unroll
  for (int o = 32; o > 0; o >>= 1) { s += __shfl_down(s, o, 64); sq += __shfl_down(sq, o, 64); }
  if ((t & 63) == 0) { red[(t >> 6) * 2] = s; red[(t >> 6) * 2 + 1] = sq; }
  __syncthreads();
  s  = red[0] + red[2] + red[4] + red[6];
  sq = red[1] + red[3] + red[5] + red[7];
  float mu = s * (1.f / 768.f);
  float var = sq * (1.f / 768.f) - mu * mu;
  float rs = rsqrtf(var + 1e-5f);
#pragma unroll
  for (int q = 0; q < 3; ++q) {
    int e = t + (q << 8);
    L1[b * 768 + e] = (y[q] - mu) * rs * g1[e] + be1[e];
  }
}

// ---------------- C1[b,:] = b1 + L1[b,:] @ W1 -----------------------------------
__global__ void c1_kernel(const float* __restrict__ L1, const float* __restrict__ W1,
                          const float* __restrict__ b1, float* __restrict__ C1) {
  int bid = blockIdx.x;          // 384 = b(8)*48
  int b = bid / 48, c = bid % 48;
  int t = threadIdx.x;
  __shared__ float Ls[768];
  __shared__ float red[8][32];
  for (int q = t; q < 768; q += 256) Ls[q] = L1[b * 768 + q];
  __syncthreads();
  int tc = t & 31, ts = t >> 5;
  int n = c * 32 + tc;
  float acc = 0.f;
  int j0 = ts * 96;
#pragma unroll 4
  for (int j = j0; j < j0 + 96; ++j) acc += Ls[j] * W1[(size_t)j * HID_ + n];
  red[ts][tc] = acc;
  __syncthreads();
  if (ts == 0) {
    float s = b1[n];
#pragma unroll
    for (int k = 0; k < 8; ++k) s += red[k][tc];
    C1[b * HID_ + n] = s;
  }
}

// ---------------- bf16 MFMA GEMM, flatmm-lite: B via LDS, A global->reg pipelined
// MODE 0 (gemm1): full K=768, bias=C1[batch], GELU, bf16 out0. grid 768.
// MODE 1 (gemm2): split-K2, no bias/GELU; bf16 partial to (kk==0?out0:out1).
template <int MODE>
__global__ __launch_bounds__(256) void gemm_bt_kernel(
    const u16* __restrict__ A, const u16* __restrict__ BT,
    const float* __restrict__ bias, void* __restrict__ out0, void* __restrict__ out1,
    int N, int lda, int ldb) {
  __shared__ __align__(16) u16 Bs[128 * 64];
  int bid = blockIdx.x;
  int xcd = bid & 7, idx = bid >> 3;
  int mloc, n_, k_off, kk = 0;
  if (MODE == 0) { mloc = idx / 12; n_ = idx % 12; k_off = 0; }
  else           { kk = idx / 48; int rem = idx % 48; mloc = rem / 6; n_ = rem % 6; k_off = kk * 768; }
  int bm = (xcd * 8 + mloc) << 7, bn = n_ << 7;

  int t = threadIdx.x;
  int lane = t & 63, w = t >> 6;
  int wm = (w >> 1) << 6, wn = (w & 1) << 6;
  int quad = lane >> 4, l16 = lane & 15;
  f32x4 acc[4][4] = {};

  // Per-thread A-fragment row pointers (rows wm+mt*16+l16), k_off folded in.
  const u16* arow[4];
#pragma unroll
  for (int mt = 0; mt < 4; ++mt)
    arow[mt] = A + (size_t)(bm + wm + (mt << 4) + l16) * lda + k_off;

  // Preload ks=0 A-fragments for k0=0.
  bf16x8 a0[4], a1[4];
#pragma unroll
  for (int mt = 0; mt < 4; ++mt)
    a0[mt] = *reinterpret_cast<const bf16x8*>(arow[mt] + (quad << 3));

  for (int k0 = 0; k0 < 768; k0 += 64) {
    // Stage B tile (16 KB) via global_load_lds, XOR-swizzled.
#pragma unroll
    for (int i = 0; i < 4; ++i) {
      int ci = t + (i << 8);           // chunk index 0..1023
      int r = ci >> 3, csw = ci & 7;
      int kc = csw ^ (r & 7);
      GLDS16(BT + (size_t)(bn + r) * ldb + k_off + k0 + (kc << 3), Bs + ci * 8);
    }
    __syncthreads();                   // drains vmcnt: Bs ready, a0 arrived

    // Issue ks=1 A-frags for THIS k0 (overlap with ks=0 MFMAs).
#pragma unroll
    for (int mt = 0; mt < 4; ++mt)
      a1[mt] = *reinterpret_cast<const bf16x8*>(arow[mt] + k0 + ((4 + quad) << 3));

    // ks = 0 MFMAs with preloaded a0.
    {
      int kc = quad;
      bf16x8 bf[4];
#pragma unroll
      for (int nt = 0; nt < 4; ++nt) {
        int row = wn + (nt << 4) + l16;
        bf[nt] = *reinterpret_cast<const bf16x8*>(Bs + row * 64 + ((kc ^ (row & 7)) << 3));
      }
#pragma unroll
      for (int mt = 0; mt < 4; ++mt)
#pragma unroll
        for (int nt = 0; nt < 4; ++nt)
          acc[mt][nt] = __builtin_amdgcn_mfma_f32_16x16x32_bf16(a0[mt], bf[nt], acc[mt][nt], 0, 0, 0);
    }

    // Prefetch ks=0 A-frags for NEXT k0 (fly across the barrier).
    if (k0 + 64 < 768) {
#pragma unroll
      for (int mt = 0; mt < 4; ++mt)
        a0[mt] = *reinterpret_cast<const bf16x8*>(arow[mt] + k0 + 64 + (quad << 3));
    }

    // ks = 1 MFMAs with a1.
    {
      int kc = 4 + quad;
      bf16x8 bf[4];
#pragma unroll
      for (int nt = 0; nt < 4; ++nt) {
        int row = wn + (nt << 4) + l16;
        bf[nt] = *reinterpret_cast<const bf16x8*>(Bs + row * 64 + ((kc ^ (row & 7)) << 3));
      }
#pragma unroll
      for (int mt = 0; mt < 4; ++mt)
#pragma unroll
        for (int nt = 0; nt < 4; ++nt)
          acc[mt][nt] = __builtin_amdgcn_mfma_f32_16x16x32_bf16(a1[mt], bf[nt], acc[mt][nt], 0, 0, 0);
    }
    __syncthreads();                   // Bs reads done before next-iter overwrite
  }

#pragma unroll
  for (int mt = 0; mt < 4; ++mt) {
    int row0 = bm + wm + (mt << 4) + (quad << 2);
#pragma unroll
    for (int nt = 0; nt < 4; ++nt) {
      int col = bn + wn + (nt << 4) + l16;
      float bv = (MODE == 0) ? bias[(bm >> 10) * N + col] : 0.f;
#pragma unroll
      for (int rr = 0; rr < 4; ++rr) {
        float v = acc[mt][nt][rr] + bv;
        size_t idxo = (size_t)(row0 + rr) * N + col;
        if (MODE == 0)       ((u16*)out0)[idxo] = f2bf(gelu_f(v));
        else if (kk == 0)    ((u16*)out0)[idxo] = f2bf(v);
        else                 ((u16*)out1)[idxo] = f2bf(v);
      }
    }
  }
}

// ---------------- LN2: m = GELU(p0+p1+b2); out = x + LN(m)*g2 + be2 -------------
__global__ void ln2_kernel(const u16* __restrict__ p0, const u16* __restrict__ p1,
                           const float* __restrict__ x, const float* __restrict__ b2,
                           const float* __restrict__ g2, const float* __restrict__ be2,
                           float* __restrict__ out) {
  int row = blockIdx.x, t = threadIdx.x;
  const u16* pr = p0 + (size_t)row * 768;
  const u16* qr = p1 + (size_t)row * 768;
  float v0 = gelu_f(bf2f(pr[t])       + bf2f(qr[t])       + b2[t]);
  float v1 = gelu_f(bf2f(pr[t + 256]) + bf2f(qr[t + 256]) + b2[t + 256]);
  float v2 = gelu_f(bf2f(pr[t + 512]) + bf2f(qr[t + 512]) + b2[t + 512]);
  float s = v0 + v1 + v2;
  float sq = v0 * v0 + v1 * v1 + v2 * v2;
  __shared__ float red[8];
#pragma unroll
  for (int o = 32; o > 0; o >>= 1) { s += __shfl_down(s, o, 64); sq += __shfl_down(sq, o, 64); }
  if ((t & 63) == 0) { red[(t >> 6) * 2] = s; red[(t >> 6) * 2 + 1] = sq; }
  __syncthreads();
  s  = red[0] + red[2] + red[4] + red[6];
  sq = red[1] + red[3] + red[5] + red[7];
  float mu = s * (1.f / 768.f);
  float var = sq * (1.f / 768.f) - mu * mu;
  float rs = rsqrtf(var + 1e-5f);
  const float* xr = x + (size_t)row * 768;
  float* orow = out + (size_t)row * 768;
  orow[t]       = xr[t]       + (v0 - mu) * rs * g2[t]       + be2[t];
  orow[t + 256] = xr[t + 256] + (v1 - mu) * rs * g2[t + 256] + be2[t + 256];
  orow[t + 512] = xr[t + 512] + (v2 - mu) * rs * g2[t + 512] + be2[t + 512];
}

extern "C" void kernel_launch(void* const* d_in, const int* in_sizes, int n_in,
                              void* d_out, int out_size, void* d_ws, size_t ws_size,
                              hipStream_t stream) {
  const float* x   = (const float*)d_in[0];
  // d_in[1]=Wq, d_in[2]=Wk are mathematically dead (softmax rows sum to 1).
  const float* Wv  = (const float*)d_in[3];
  const float* W1  = (const float*)d_in[4];
  const float* b1  = (const float*)d_in[5];
  const float* W2  = (const float*)d_in[6];
  const float* b2  = (const float*)d_in[7];
  const float* g1  = (const float*)d_in[8];
  const float* be1 = (const float*)d_in[9];
  const float* g2  = (const float*)d_in[10];
  const float* be2 = (const float*)d_in[11];
  float* out = (float*)d_out;

  char* ws = (char*)d_ws;
  u16*   xb  = (u16*)(ws);                       // 12,582,912 B  (8192x768 bf16)
  u16*   W1T = (u16*)(ws + 12582912);            //  2,359,296 B  (1536x768 bf16)
  u16*   W2T = (u16*)(ws + 14942208);            //  2,359,296 B  (768x1536 bf16)
  u16*   h   = (u16*)(ws + 17301504);            // 25,165,824 B  (8192x1536 bf16)
  // Rp ALIASES h: Rp consumed by ygemm before gemm1 writes h (same stream).
  float* Rp  = (float*)(ws + 17301504);          // 14,155,776 B  (384x9216 f32)
  float* P3  = (float*)(ws + 42467328);          //  2,359,296 B  (96x96x64 f32)
  float* L1  = (float*)(ws + 44826624);          //     24,576 B  (8x768 f32)
  float* C1  = (float*)(ws + 44851200);          //     49,152 B  (8x1536 f32)
  u16*   m0  = (u16*)(ws + 44900352);            // 12,582,912 B  (8192x768 bf16) gemm2 kk=0 partial
  // p1 ALIASES xb: xb dead after gemm1; gemm2 half-1 partial (bf16) lives there.
  u16*   p1  = xb;

  prep_kernel<<<6720, 256, 0, stream>>>(x, W1, W2, xb, W1T, W2T);
  rowsum_kernel<<<384, 256, 0, stream>>>(xb, Rp);
  ygemm_kernel<<<dim3(12, 96, 8), 256, 0, stream>>>(Rp, Wv, P3);
  ln1_kernel<<<8, 256, 0, stream>>>(P3, g1, be1, L1);
  c1_kernel<<<384, 256, 0, stream>>>(L1, W1, b1, C1);
  gemm_bt_kernel<0><<<768, 256, 0, stream>>>(xb, W1T, C1, (void*)h, nullptr, 1536, 768, 768);
  gemm_bt_kernel<1><<<768, 256, 0, stream>>>(h, W2T, nullptr, (void*)m0, (void*)p1, 768, 1536, 1536);
  ln2_kernel<<<8192, 256, 0, stream>>>(m0, p1, x, b2, g2, be2, out);
}

// Round 6
// 234.385 us; speedup vs baseline: 1.3588x; 1.3588x over previous
//
#include <hip/hip_runtime.h>
#include <hip/hip_bf16.h>
#include <math.h>

#define E_ 768
#define HID_ 1536
#define SQ_ 1024

typedef unsigned short u16;
using bf16x8 = __attribute__((ext_vector_type(8))) __bf16;
using f32x4  = __attribute__((ext_vector_type(4))) float;

__device__ __forceinline__ u16 f2bf(float f) {
  union { float f; unsigned u; } v; v.f = f;
  unsigned r = v.u + 0x7FFFu + ((v.u >> 16) & 1u);
  return (u16)(r >> 16);
}
__device__ __forceinline__ float bf2f(u16 h) {
  union { unsigned u; float f; } v; v.u = ((unsigned)h) << 16; return v.f;
}
__device__ __forceinline__ float gelu_f(float x) {
  return 0.5f * x * (1.0f + erff(x * 0.70710678118654752f));
}

#define GLDS16(gp, sp) __builtin_amdgcn_global_load_lds( \
    (__attribute__((address_space(1))) const void*)(const void*)(gp), \
    (__attribute__((address_space(3))) void*)(void*)(sp), 16, 0, 0)

// ---------------- prep: cast x -> bf16; LDS-tiled transpose-cast W1->W1T, W2->W2T
__global__ void prep_kernel(const float* __restrict__ x, const float* __restrict__ W1,
                            const float* __restrict__ W2, u16* __restrict__ xb,
                            u16* __restrict__ W1T, u16* __restrict__ W2T) {
  __shared__ float T[64 * 65];
  int bid = blockIdx.x, t = threadIdx.x;
  if (bid < 6144) {                       // x: 6144*1024 = 6291456 elems
    int base = bid * 1024 + t * 4;
    const float4 v = *reinterpret_cast<const float4*>(x + base);
    ushort4 o; o.x = f2bf(v.x); o.y = f2bf(v.y); o.z = f2bf(v.z); o.w = f2bf(v.w);
    *reinterpret_cast<ushort4*>(xb + base) = o;
    return;
  }
  const float* in; u16* out; int R_in, C_in, rt, ct;
  if (bid < 6432) {                       // W1 (768 x 1536) -> W1T (1536 x 768)
    int b2 = bid - 6144; in = W1; out = W1T; R_in = 768; C_in = 1536;
    rt = b2 / 24; ct = b2 % 24;
  } else {                                // W2 (1536 x 768) -> W2T (768 x 1536)
    int b3 = bid - 6432; in = W2; out = W2T; R_in = 1536; C_in = 768;
    rt = b3 / 12; ct = b3 % 12;
  }
  int r0 = rt << 6, c0 = ct << 6;
  int tr = t >> 4, tc4 = (t & 15) << 2;
#pragma unroll
  for (int i = 0; i < 4; ++i) {
    int row = tr + (i << 4);
    const float4 v = *reinterpret_cast<const float4*>(in + (size_t)(r0 + row) * C_in + c0 + tc4);
    T[row * 65 + tc4 + 0] = v.x;
    T[row * 65 + tc4 + 1] = v.y;
    T[row * 65 + tc4 + 2] = v.z;
    T[row * 65 + tc4 + 3] = v.w;
  }
  __syncthreads();
#pragma unroll
  for (int i = 0; i < 4; ++i) {
    int orow = tr + (i << 4);
    ushort4 o;
    o.x = f2bf(T[(tc4 + 0) * 65 + orow]);
    o.y = f2bf(T[(tc4 + 1) * 65 + orow]);
    o.z = f2bf(T[(tc4 + 2) * 65 + orow]);
    o.w = f2bf(T[(tc4 + 3) * 65 + orow]);
    *reinterpret_cast<ushort4*>(out + (size_t)(c0 + orow) * R_in + r0 + tc4) = o;
  }
}

// ---------------- rowsum partials over 4 s-chunks (reads bf16 xb) ---------------
__global__ void rowsum_kernel(const u16* __restrict__ xb, float* __restrict__ Rp) {
  int bid = blockIdx.x;          // 384 = r(96)*4 + c
  int r = bid >> 2, c = bid & 3;
  int b = r / 12, n = r % 12;
  int t = threadIdx.x;
  int u0 = n << 10;
  int s_lo = u0 / 12;
  int s_hi = (u0 + 1023) / 12;
  int cnt = s_hi - s_lo + 1;
  int cs = s_lo + (cnt * c) / 4;
  int ce = s_lo + (cnt * (c + 1)) / 4;
  float acc[12][3];
#pragma unroll
  for (int g = 0; g < 12; ++g)
    for (int q = 0; q < 3; ++q) acc[g][q] = 0.f;
  const u16* xp = xb + (size_t)b * SQ_ * E_;
  for (int s = cs; s < ce; ++s) {
    float v0 = bf2f(xp[(size_t)s * E_ + t]);
    float v1 = bf2f(xp[(size_t)s * E_ + t + 256]);
    float v2 = bf2f(xp[(size_t)s * E_ + t + 512]);
    int du = 12 * s - u0;
#pragma unroll
    for (int g = 0; g < 12; ++g) {
      int u = du + g;
      if (u >= 0 && u < 1024) { acc[g][0] += v0; acc[g][1] += v1; acc[g][2] += v2; }
    }
  }
  float* Rr = Rp + (size_t)bid * 9216;
#pragma unroll
  for (int g = 0; g < 12; ++g) {
    Rr[g * 768 + t]       = acc[g][0];
    Rr[g * 768 + t + 256] = acc[g][1];
    Rr[g * 768 + t + 512] = acc[g][2];
  }
}

// ---- P3[r][g][jc][d] = sum_{j in jc-chunk} (sum_c Rp[r,c,g,j]) * Wv[j, g*64+d] -
__global__ void ygemm_kernel(const float* __restrict__ Rp, const float* __restrict__ Wv,
                             float* __restrict__ P3) {
  int g = blockIdx.x, r = blockIdx.y, jc = blockIdx.z;   // (12, 96, 8)
  int t = threadIdx.x;
  int d = t & 63, sub = t >> 6;
  const float* R0 = Rp + (size_t)r * 4 * 9216 + g * 768;
  const float* wp = Wv + g * 64 + d;
  int j0 = jc * 96 + sub * 24;
  float a0 = 0.f, a1 = 0.f, a2 = 0.f, a3 = 0.f;
#pragma unroll
  for (int jj = 0; jj < 24; jj += 4) {
    int j = j0 + jj;
    float r0v = R0[j + 0] + R0[9216 + j + 0] + R0[18432 + j + 0] + R0[27648 + j + 0];
    float r1v = R0[j + 1] + R0[9216 + j + 1] + R0[18432 + j + 1] + R0[27648 + j + 1];
    float r2v = R0[j + 2] + R0[9216 + j + 2] + R0[18432 + j + 2] + R0[27648 + j + 2];
    float r3v = R0[j + 3] + R0[9216 + j + 3] + R0[18432 + j + 3] + R0[27648 + j + 3];
    a0 += r0v * wp[(size_t)(j + 0) * 768];
    a1 += r1v * wp[(size_t)(j + 1) * 768];
    a2 += r2v * wp[(size_t)(j + 2) * 768];
    a3 += r3v * wp[(size_t)(j + 3) * 768];
  }
  __shared__ float red[256];
  red[t] = (a0 + a1) + (a2 + a3);
  __syncthreads();
  if (sub == 0)
    P3[(((size_t)r * 12 + g) * 8 + jc) * 64 + d] = red[d] + red[64 + d] + red[128 + d] + red[192 + d];
}

// ---------------- ysum: Y[b*768 + n*64 + d] = sum over 96 partials --------------
__global__ void ysum_kernel(const float* __restrict__ P3, float* __restrict__ Y) {
  int bn = blockIdx.x;            // 0..95 = b*12+n
  int t = threadIdx.x;
  int d = t & 63, sub = t >> 6;   // sub 0..3
  const float* Pp = P3 + (size_t)bn * 6144 + d;
  int g0 = sub * 24;
  float s = 0.f;
#pragma unroll 8
  for (int gj = 0; gj < 24; ++gj) s += Pp[(g0 + gj) << 6];
  __shared__ float red[256];
  red[t] = s;
  __syncthreads();
  if (sub == 0)
    Y[bn * 64 + d] = red[d] + red[64 + d] + red[128 + d] + red[192 + d];
}

// ---------------- LN1 over Y[b,:] (768) -> L1[b,:] ------------------------------
__global__ void ln1_kernel(const float* __restrict__ Y, const float* __restrict__ g1,
                           const float* __restrict__ be1, float* __restrict__ L1) {
  int b = blockIdx.x, t = threadIdx.x;
  float y0 = Y[b * 768 + t];
  float y1 = Y[b * 768 + t + 256];
  float y2 = Y[b * 768 + t + 512];
  float s = y0 + y1 + y2;
  float sq = y0 * y0 + y1 * y1 + y2 * y2;
  __shared__ float red[8];
#pragma unroll
  for (int o = 32; o > 0; o >>= 1) { s += __shfl_down(s, o, 64); sq += __shfl_down(sq, o, 64); }
  if ((t & 63) == 0) { red[(t >> 6) * 2] = s; red[(t >> 6) * 2 + 1] = sq; }
  __syncthreads();
  s  = red[0] + red[2] + red[4] + red[6];
  sq = red[1] + red[3] + red[5] + red[7];
  float mu = s * (1.f / 768.f);
  float var = sq * (1.f / 768.f) - mu * mu;
  float rs = rsqrtf(var + 1e-5f);
  L1[b * 768 + t]       = (y0 - mu) * rs * g1[t]       + be1[t];
  L1[b * 768 + t + 256] = (y1 - mu) * rs * g1[t + 256] + be1[t + 256];
  L1[b * 768 + t + 512] = (y2 - mu) * rs * g1[t + 512] + be1[t + 512];
}

// ---------------- C1[b,:] = b1 + L1[b,:] @ W1 -----------------------------------
__global__ void c1_kernel(const float* __restrict__ L1, const float* __restrict__ W1,
                          const float* __restrict__ b1, float* __restrict__ C1) {
  int bid = blockIdx.x;          // 384 = b(8)*48
  int b = bid / 48, c = bid % 48;
  int t = threadIdx.x;
  __shared__ float Ls[768];
  __shared__ float red[8][32];
  for (int q = t; q < 768; q += 256) Ls[q] = L1[b * 768 + q];
  __syncthreads();
  int tc = t & 31, ts = t >> 5;
  int n = c * 32 + tc;
  float acc = 0.f;
  int j0 = ts * 96;
#pragma unroll 4
  for (int j = j0; j < j0 + 96; ++j) acc += Ls[j] * W1[(size_t)j * HID_ + n];
  red[ts][tc] = acc;
  __syncthreads();
  if (ts == 0) {
    float s = b1[n];
#pragma unroll
    for (int k = 0; k < 8; ++k) s += red[k][tc];
    C1[b * HID_ + n] = s;
  }
}

// ---------------- bf16 MFMA GEMM, XCD-swizzled flat grid (r4 known-good) --------
// MODE 0 (gemm1): full K=768, bias=C1[batch], GELU, bf16 out0. grid 768.
// MODE 1 (gemm2): split-K2, no bias/GELU; bf16 partial to (kk==0?out0:out1).
template <int MODE>
__global__ __launch_bounds__(256, 2) void gemm_bt_kernel(
    const u16* __restrict__ A, const u16* __restrict__ BT,
    const float* __restrict__ bias, void* __restrict__ out0, void* __restrict__ out1,
    int N, int lda, int ldb) {
  __shared__ __align__(16) u16 As[128 * 64];
  __shared__ __align__(16) u16 Bs[128 * 64];
  int bid = blockIdx.x;
  int xcd = bid & 7, idx = bid >> 3;
  int mloc, n_, k_off, kk = 0;
  if (MODE == 0) { mloc = idx / 12; n_ = idx % 12; k_off = 0; }
  else           { kk = idx / 48; int rem = idx % 48; mloc = rem / 6; n_ = rem % 6; k_off = kk * 768; }
  int bm = (xcd * 8 + mloc) << 7, bn = n_ << 7;

  int t = threadIdx.x;
  int lane = t & 63, w = t >> 6;
  int wm = (w >> 1) << 6, wn = (w & 1) << 6;
  int quad = lane >> 4, l16 = lane & 15;
  f32x4 acc[4][4] = {};

  for (int k0 = 0; k0 < 768; k0 += 64) {
    __syncthreads();
#pragma unroll
    for (int i = 0; i < 4; ++i) {
      int ci = t + (i << 8);           // chunk index 0..1023
      int r = ci >> 3, csw = ci & 7;   // LDS slot (r, csw)
      int kc = csw ^ (r & 7);          // XOR swizzle
      const u16* ga = A + (size_t)(bm + r) * lda + k_off + k0 + (kc << 3);
      GLDS16(ga, As + ci * 8);
      const u16* gb = BT + (size_t)(bn + r) * ldb + k_off + k0 + (kc << 3);
      GLDS16(gb, Bs + ci * 8);
    }
    __builtin_amdgcn_s_waitcnt(0);
    __syncthreads();
#pragma unroll
    for (int ks = 0; ks < 2; ++ks) {
      bf16x8 af[4], bf[4];
      int kc = (ks << 2) + quad;
#pragma unroll
      for (int mt = 0; mt < 4; ++mt) {
        int row = wm + (mt << 4) + l16;
        af[mt] = *reinterpret_cast<const bf16x8*>(As + row * 64 + ((kc ^ (row & 7)) << 3));
      }
#pragma unroll
      for (int nt = 0; nt < 4; ++nt) {
        int row = wn + (nt << 4) + l16;
        bf[nt] = *reinterpret_cast<const bf16x8*>(Bs + row * 64 + ((kc ^ (row & 7)) << 3));
      }
#pragma unroll
      for (int mt = 0; mt < 4; ++mt)
#pragma unroll
        for (int nt = 0; nt < 4; ++nt)
          acc[mt][nt] = __builtin_amdgcn_mfma_f32_16x16x32_bf16(af[mt], bf[nt], acc[mt][nt], 0, 0, 0);
    }
  }

#pragma unroll
  for (int mt = 0; mt < 4; ++mt) {
    int row0 = bm + wm + (mt << 4) + (quad << 2);
#pragma unroll
    for (int nt = 0; nt < 4; ++nt) {
      int col = bn + wn + (nt << 4) + l16;
      float bv = (MODE == 0) ? bias[(bm >> 10) * N + col] : 0.f;
#pragma unroll
      for (int rr = 0; rr < 4; ++rr) {
        float v = acc[mt][nt][rr] + bv;
        size_t idxo = (size_t)(row0 + rr) * N + col;
        if (MODE == 0)       ((u16*)out0)[idxo] = f2bf(gelu_f(v));
        else if (kk == 0)    ((u16*)out0)[idxo] = f2bf(v);
        else                 ((u16*)out1)[idxo] = f2bf(v);
      }
    }
  }
}

// ---------------- LN2: m = GELU(p0+p1+b2); out = x + LN(m)*g2 + be2 (vectorized) -
__global__ void ln2_kernel(const u16* __restrict__ p0, const u16* __restrict__ p1,
                           const float* __restrict__ x, const float* __restrict__ b2,
                           const float* __restrict__ g2, const float* __restrict__ be2,
                           float* __restrict__ out) {
  int row = blockIdx.x, t = threadIdx.x;
  float v0 = 0.f, v1 = 0.f, v2 = 0.f, v3 = 0.f;
  float s = 0.f, sq = 0.f;
  int e = t << 2;
  if (t < 192) {
    ushort4 pa = *reinterpret_cast<const ushort4*>(p0 + (size_t)row * 768 + e);
    ushort4 pb = *reinterpret_cast<const ushort4*>(p1 + (size_t)row * 768 + e);
    float4 bb = *reinterpret_cast<const float4*>(b2 + e);
    v0 = gelu_f(bf2f(pa.x) + bf2f(pb.x) + bb.x);
    v1 = gelu_f(bf2f(pa.y) + bf2f(pb.y) + bb.y);
    v2 = gelu_f(bf2f(pa.z) + bf2f(pb.z) + bb.z);
    v3 = gelu_f(bf2f(pa.w) + bf2f(pb.w) + bb.w);
    s = (v0 + v1) + (v2 + v3);
    sq = (v0 * v0 + v1 * v1) + (v2 * v2 + v3 * v3);
  }
  __shared__ float red[8];
#pragma unroll
  for (int o = 32; o > 0; o >>= 1) { s += __shfl_down(s, o, 64); sq += __shfl_down(sq, o, 64); }
  if ((t & 63) == 0) { red[(t >> 6) * 2] = s; red[(t >> 6) * 2 + 1] = sq; }
  __syncthreads();
  s  = red[0] + red[2] + red[4];   // wave 3 contributes zero
  sq = red[1] + red[3] + red[5];
  float mu = s * (1.f / 768.f);
  float var = sq * (1.f / 768.f) - mu * mu;
  float rs = rsqrtf(var + 1e-5f);
  if (t < 192) {
    float4 gg = *reinterpret_cast<const float4*>(g2 + e);
    float4 be = *reinterpret_cast<const float4*>(be2 + e);
    float4 xx = *reinterpret_cast<const float4*>(x + (size_t)row * 768 + e);
    float4 o;
    o.x = xx.x + (v0 - mu) * rs * gg.x + be.x;
    o.y = xx.y + (v1 - mu) * rs * gg.y + be.y;
    o.z = xx.z + (v2 - mu) * rs * gg.z + be.z;
    o.w = xx.w + (v3 - mu) * rs * gg.w + be.w;
    *reinterpret_cast<float4*>(out + (size_t)row * 768 + e) = o;
  }
}

extern "C" void kernel_launch(void* const* d_in, const int* in_sizes, int n_in,
                              void* d_out, int out_size, void* d_ws, size_t ws_size,
                              hipStream_t stream) {
  const float* x   = (const float*)d_in[0];
  // d_in[1]=Wq, d_in[2]=Wk are mathematically dead (softmax rows sum to 1).
  const float* Wv  = (const float*)d_in[3];
  const float* W1  = (const float*)d_in[4];
  const float* b1  = (const float*)d_in[5];
  const float* W2  = (const float*)d_in[6];
  const float* b2  = (const float*)d_in[7];
  const float* g1  = (const float*)d_in[8];
  const float* be1 = (const float*)d_in[9];
  const float* g2  = (const float*)d_in[10];
  const float* be2 = (const float*)d_in[11];
  float* out = (float*)d_out;

  char* ws = (char*)d_ws;
  u16*   xb  = (u16*)(ws);                       // 12,582,912 B  (8192x768 bf16)
  u16*   W1T = (u16*)(ws + 12582912);            //  2,359,296 B  (1536x768 bf16)
  u16*   W2T = (u16*)(ws + 14942208);            //  2,359,296 B  (768x1536 bf16)
  u16*   h   = (u16*)(ws + 17301504);            // 25,165,824 B  (8192x1536 bf16)
  // Rp ALIASES h: Rp consumed by ygemm before gemm1 writes h (same stream).
  float* Rp  = (float*)(ws + 17301504);          // 14,155,776 B  (384x9216 f32)
  float* P3  = (float*)(ws + 42467328);          //  2,359,296 B  (96x96x64 f32)
  float* Y   = (float*)(ws + 44826624);          //     24,576 B  (8x768 f32)
  float* L1  = (float*)(ws + 44851200);          //     24,576 B  (8x768 f32)
  float* C1  = (float*)(ws + 44875776);          //     49,152 B  (8x1536 f32)
  u16*   m0  = (u16*)(ws + 44924928);            // 12,582,912 B  (8192x768 bf16) gemm2 kk=0 partial
  // p1 ALIASES xb: xb dead after gemm1; gemm2 half-1 partial (bf16) lives there.
  u16*   p1  = xb;

  prep_kernel<<<6720, 256, 0, stream>>>(x, W1, W2, xb, W1T, W2T);
  rowsum_kernel<<<384, 256, 0, stream>>>(xb, Rp);
  ygemm_kernel<<<dim3(12, 96, 8), 256, 0, stream>>>(Rp, Wv, P3);
  ysum_kernel<<<96, 256, 0, stream>>>(P3, Y);
  ln1_kernel<<<8, 256, 0, stream>>>(Y, g1, be1, L1);
  c1_kernel<<<384, 256, 0, stream>>>(L1, W1, b1, C1);
  gemm_bt_kernel<0><<<768, 256, 0, stream>>>(xb, W1T, C1, (void*)h, nullptr, 1536, 768, 768);
  gemm_bt_kernel<1><<<768, 256, 0, stream>>>(h, W2T, nullptr, (void*)m0, (void*)p1, 768, 1536, 1536);
  ln2_kernel<<<8192, 256, 0, stream>>>(m0, p1, x, b2, g2, be2, out);
}